// Round 13
// baseline (638021.387 us; speedup 1.0000x reference)
//
#include <hip/hip_runtime.h>
#include <hip/hip_bf16.h>
#include <math.h>

#define BATCH 128
#define TT 800
#define SL 64
#define AA 60
#define HH 400
#define KK 10
#define MB 8            // batches per group
#define NG 16           // groups
#define GWG 8           // WGs per group (NG*GWG = 128 blocks)
#define NTHR 512
#define TPW 7           // gate waves (each owns up to 2 tiles); wave 7 = p-dot
#define NTILE 104       // 100 real + 4 dummy unit-gate tiles (13 per WG)
#define NKT 15          // K tiles: K=480 = [x:3|w:60|0:1|h:400|0:16]
#define AST 488         // Abuf row stride (shorts)
#define NPF 26          // Wp fragments
#define OHST 72         // transposed onehots l-stride (shorts)
#define UPG 50          // hid1 unit-slice per WG (HH/GWG)
#define CPG 800         // h-chunks per group (400 units x 2 batch-quads)

#define O_HF   (BATCH*TT*HH)
#define O_CF   (O_HF + BATCH*HH)
#define O_WIN  (O_CF + BATCH*HH)
#define O_WF   (O_WIN + BATCH*TT*AA)
#define O_KF   (O_WF + BATCH*AA)
#define O_PHI  (O_KF + BATCH*KK)

// ws: tagged h-chunks [2][NG][CPG][4 floats] | gate pack | Wp pack
#define HCH_N (2*NG*CPG*4)              // zeroed each launch
#define PK_S  (HCH_N*2)
#define GATE_FRAGS (NTILE*NKT)
#define PPK_S (PK_S + GATE_FRAGS*512)

// dynamic LDS partition (bytes)
#define SM_ABUF  0                            // 16 rows (8 real) x AST shorts
#define SM_OHB   (SM_ABUF + 16*AST*2)         // 15616
#define SM_PHIB  (SM_OHB + MB*AA*OHST*2)      // 84736
#define SM_PBUF  (SM_PHIB + MB*66*4)          // 86848
#define SM_AVB   (SM_PBUF + 30*MB*4)          // 87808
#define SM_BVB   (SM_AVB + KK*MB*4)           // 88128
#define SM_KVB   (SM_BVB + KK*MB*4)           // 88448
#define SM_SCALE (SM_KVB + KK*MB*4)           // 88768
#define SMEM_BYTES (SM_SCALE + 64)            // 88832

typedef __attribute__((ext_vector_type(8))) short bf16x8;
typedef __attribute__((ext_vector_type(4))) float f32x4;
typedef __attribute__((ext_vector_type(4))) unsigned u32x4;

__device__ __forceinline__ void llc_ld4(f32x4& r, const float* p) {
  asm volatile("global_load_dwordx4 %0, %1, off sc1" : "=&v"(r) : "v"(p) : "memory");
}
__device__ __forceinline__ void llc_st4(float* p, f32x4 v) {
  asm volatile("global_store_dwordx4 %0, %1, off sc1" :: "v"(p), "v"(v) : "memory");
}
__device__ __forceinline__ void vm_drain() {
  asm volatile("s_waitcnt vmcnt(0)" ::: "memory");
  __builtin_amdgcn_sched_barrier(0);
}
__device__ __forceinline__ unsigned bf16bits(float x) {
  __hip_bfloat16 hb = __float2bfloat16(x);
  return (unsigned)*reinterpret_cast<unsigned short*>(&hb);
}

__global__ void prep_pack(const float* __restrict__ W_ih, const float* __restrict__ W_hh,
                          const float* __restrict__ Wp, short* __restrict__ dst) {
  int tid = blockIdx.x*256 + threadIdx.x;
  const int NWT = GATE_FRAGS*64;
  if (tid < NWT) {
    int l = tid & 63;
    int kt = (tid >> 6) % NKT;
    int tt = (tid >> 6) / NKT;
    int nn = l & 15;
    int gt = nn >> 2, du = nn & 3;
    int u = tt*4 + du;
    int kb = kt*32 + (l>>4)*8;
    __align__(16) short v[8];
    #pragma unroll
    for (int j = 0; j < 8; ++j) {
      int k = kb + j;
      float x = 0.f;
      if (u < HH) {
        if (k < 63) x = W_ih[(size_t)(gt*HH+u)*63 + k];
        else if (k >= 64 && k < 464) x = W_hh[(size_t)(gt*HH+u)*HH + (k-64)];
      }
      __hip_bfloat16 hb = __float2bfloat16(x);
      v[j] = *reinterpret_cast<short*>(&hb);
    }
    *(bf16x8*)(dst + (size_t)PK_S + (size_t)tid*8) = *(const bf16x8*)v;
  } else if (tid < NWT + NPF*64) {
    int r = tid - NWT;
    int l = r & 63;
    int idx = r >> 6;
    int kt = idx % 13;
    int tp = idx / 13;
    int jj = tp*16 + (l&15);
    int kb = (kt+2)*32 + (l>>4)*8;
    __align__(16) short v[8];
    #pragma unroll
    for (int j = 0; j < 8; ++j) {
      int k = kb + j;
      float x = (jj < 3*KK && k >= 64 && k < 464) ? Wp[(size_t)jj*HH + (k-64)] : 0.f;
      __hip_bfloat16 hb = __float2bfloat16(x);
      v[j] = *reinterpret_cast<short*>(&hb);
    }
    *(bf16x8*)(dst + (size_t)PPK_S + (size_t)r*8) = *(const bf16x8*)v;
  }
}

__global__ __launch_bounds__(NTHR, 1) void lstm_split(
    const float* __restrict__ strks, const float* __restrict__ onehots,
    const float* __restrict__ sents_m, const float* __restrict__ w_prev,
    const float* __restrict__ k_prev, const float* __restrict__ h0,
    const float* __restrict__ c0, const float* __restrict__ b_ih,
    const float* __restrict__ b_hh, const float* __restrict__ bp,
    float* __restrict__ out, float* __restrict__ ws)
{
  const int g  = blockIdx.x & 15;
  const int wg = blockIdx.x >> 4;
  const int b0 = g*MB;
  const int tid = threadIdx.x;
  const int lane = tid & 63;
  const int wid = tid >> 6;
  const int nn = lane & 15, gt = nn >> 2, du = nn & 3, bq = lane >> 4;

  float* hch = ws;
  const __hip_bfloat16* gpk  = (const __hip_bfloat16*)((const short*)ws + PK_S);
  const __hip_bfloat16* gppk = (const __hip_bfloat16*)((const short*)ws + PPK_S);

  extern __shared__ __align__(16) char smem[];
  __hip_bfloat16* Abuf = (__hip_bfloat16*)(smem + SM_ABUF);   // [16 rows][k]
  __hip_bfloat16* ohb  = (__hip_bfloat16*)(smem + SM_OHB);    // [b][a][OHST]
  float* phib   = (float*)(smem + SM_PHIB);                   // [b][66]
  float* pbuf   = (float*)(smem + SM_PBUF);                   // [j][b]
  float* avb    = (float*)(smem + SM_AVB);
  float* bvb    = (float*)(smem + SM_BVB);
  float* kvb    = (float*)(smem + SM_KVB);
  float* scaleb = (float*)(smem + SM_SCALE);

  // gate tiles: 13 per WG, 2 per wave (wave 6 gets 1)
  const int tbase = wg*13 + wid*2;
  const bool has1 = (wid < 6);
  const int u0 = (wid < TPW) ? (tbase*4 + du) : HH;
  const int u1 = (wid < TPW && has1) ? ((tbase+1)*4 + du) : HH;

  float bias0 = 0.f, bias1 = 0.f, cst0[4] = {0,0,0,0}, cst1[4] = {0,0,0,0};
  if (wid < TPW) {
    if (u0 < HH) bias0 = b_ih[gt*HH+u0] + b_hh[gt*HH+u0];
    if (u1 < HH) bias1 = b_ih[gt*HH+u1] + b_hh[gt*HH+u1];
    if (bq < 2) {
      #pragma unroll
      for (int r = 0; r < 4; ++r) {
        if (u0 < HH) cst0[r] = c0[(size_t)(b0+4*bq+r)*HH + u0];
        if (u1 < HH) cst1[r] = c0[(size_t)(b0+4*bq+r)*HH + u1];
      }
    }
  }
  float pbias0 = 0.f, pbias1 = 0.f;
  if (wid == 7) {
    if (nn < 3*KK - 16) pbias1 = bp[16 + nn];
    pbias0 = bp[nn];
  }

  // weights -> registers once; wreg unioned: gates use [0..29], wave7 uses [0..25]
  bf16x8 wreg[30];
  if (wid < TPW) {
    const __hip_bfloat16* base0 = gpk + ((size_t)tbase*NKT*64 + lane)*8;
    #pragma unroll
    for (int kt = 0; kt < NKT; ++kt) wreg[kt] = *(const bf16x8*)(base0 + (size_t)kt*512);
    if (has1) {
      const __hip_bfloat16* base1 = gpk + ((size_t)(tbase+1)*NKT*64 + lane)*8;
      #pragma unroll
      for (int kt = 0; kt < NKT; ++kt) wreg[NKT+kt] = *(const bf16x8*)(base1 + (size_t)kt*512);
    }
  } else {
    const __hip_bfloat16* base = gppk + (size_t)lane*8;
    #pragma unroll
    for (int i = 0; i < NPF; ++i) wreg[i] = *(const bf16x8*)(base + (size_t)i*512);
  }

  // prologue: Abuf rows 0..7 = [x_0 | w_prev | 0 | h0 | 0], rows 8..15 zero
  for (int i = tid; i < 16*AST; i += NTHR) {
    int b = i / AST, k = i % AST;
    float v = 0.f;
    if (b < MB) {
      if (k < 3) v = strks[(size_t)(b0+b)*(TT*3) + k];
      else if (k < 63) v = w_prev[(size_t)(b0+b)*AA + (k-3)];
      else if (k >= 64 && k < 464) v = h0[(size_t)(b0+b)*HH + (k-64)];
    }
    Abuf[i] = __float2bfloat16(v);
  }
  for (int i = tid; i < MB*SL*AA; i += NTHR) {
    int b = i / (SL*AA), r = i % (SL*AA);
    int l = r / AA, a = r % AA;
    ohb[(b*AA + a)*OHST + l] = __float2bfloat16(onehots[(size_t)b0*SL*AA + i]);
  }
  for (int i = tid; i < KK*MB; i += NTHR)
    kvb[(i>>3)*MB + (i&7)] = k_prev[(size_t)(b0+(i&7))*KK + (i>>3)];
  if (tid < MB) {
    float s = 0.f;
    for (int l = 0; l < SL; ++l) s += sents_m[(size_t)(b0+tid)*SL + l];
    scaleb[tid] = (float)SL / s;
  }
  __syncthreads();

#define ACT_PUBLISH(ACC, UU, CST, CHB, SEQTAG, WRITE_FINAL) do {               \
    float vv[4], hq[4];                                                        \
    _Pragma("unroll") for (int r = 0; r < 4; ++r) {                            \
      float v = (ACC)[r];                                                      \
      float sg = 1.f/(1.f + __expf(gt==2 ? -2.f*v : -v));                      \
      vv[r] = (gt==2) ? 2.f*sg - 1.f : sg;                                     \
    }                                                                          \
    _Pragma("unroll") for (int r = 0; r < 4; ++r) {                            \
      float v = vv[r];                                                         \
      float x4 = __shfl_xor(v,4), x8 = __shfl_xor(v,8), x12 = __shfl_xor(v,12);\
      float iv = (gt==0)?v  :(gt==1)?x4 :(gt==2)?x8 :x12;                      \
      float fv = (gt==0)?x4 :(gt==1)?v  :(gt==2)?x12:x8;                       \
      float gv = (gt==0)?x8 :(gt==1)?x12:(gt==2)?v  :x4;                       \
      float ov = (gt==0)?x12:(gt==1)?x8 :(gt==2)?x4 :v;                        \
      float c = fv*(CST)[r] + iv*gv;                                           \
      (CST)[r] = c;                                                            \
      hq[r] = ov * (2.f/(1.f + __expf(-2.f*c)) - 1.f);                         \
    }                                                                          \
    if (gt == 0 && bq < 2 && (UU) < HH) {                                      \
      unsigned q01 = bf16bits(hq[0]) | (bf16bits(hq[1]) << 16);                \
      unsigned q23 = bf16bits(hq[2]) | (bf16bits(hq[3]) << 16);                \
      f32x4 ch = { __uint_as_float(q01), __uint_as_float(q23),                 \
                   __int_as_float(SEQTAG), 0.f };                              \
      llc_st4((CHB) + (size_t)4*((UU)*2 + bq), ch);                            \
      if (WRITE_FINAL) {                                                       \
        _Pragma("unroll") for (int r = 0; r < 4; ++r) {                        \
          out[O_HF + (size_t)(b0+4*bq+r)*HH + (UU)] = hq[r];                   \
          out[O_CF + (size_t)(b0+4*bq+r)*HH + (UU)] = (CST)[r];                \
        }                                                                      \
      }                                                                        \
    }                                                                          \
  } while (0)

  // prologue gates: full K -> publish h_0 (tag 1, parity 0)
  f32x4 gacc0, gacc1;
  if (wid < TPW) {
    const __hip_bfloat16* arow = Abuf + nn*AST + bq*8;
    gacc0 = (f32x4){bias0,bias0,bias0,bias0};
    gacc1 = (f32x4){bias1,bias1,bias1,bias1};
    #pragma unroll
    for (int kt = 0; kt < NKT; ++kt) {
      bf16x8 af = *(const bf16x8*)(arow + kt*32);
      gacc0 = __builtin_amdgcn_mfma_f32_16x16x32_bf16(af, wreg[kt], gacc0, 0, 0, 0);
      if (has1)
        gacc1 = __builtin_amdgcn_mfma_f32_16x16x32_bf16(af, wreg[NKT+kt], gacc1, 0, 0, 0);
    }
    float* chb0 = hch + (size_t)g*(CPG*4);
    ACT_PUBLISH(gacc0, u0, cst0, chb0, 1, false);
    if (has1) ACT_PUBLISH(gacc1, u1, cst1, chb0, 1, false);
  }
  __syncthreads();   // prologue h-region reads done before collect overwrites

  for (int s = 0; s < TT; ++s) {
    float* chb = hch + (size_t)(((s  )&1)*NG + g)*(CPG*4);  // h_s
    float* chn = hch + (size_t)(((s+1)&1)*NG + g)*(CPG*4);  // h_{s+1}

    // ---- collect h_s: speculative tagged reads (800 chunks, 2 slots/thread)
    {
      const int want = s+1;
      f32x4 c0v, c1v;
      int d0 = 0, d1 = (tid < CPG-512) ? 0 : 1;
      for (int it = 0; it < (1<<12); ++it) {
        if (!d0) llc_ld4(c0v, chb + 4*(size_t)tid);
        if (!d1) llc_ld4(c1v, chb + 4*(size_t)(tid+512));
        vm_drain();
        d0 |= (__float_as_int(c0v.z) == want);
        d1 |= (__float_as_int(c1v.z) == want);
        if (d0 & d1) break;
        if (it) __builtin_amdgcn_s_sleep(1);
      }
#define UNPACK(C, CID) do {                                                    \
    int uu = (CID) >> 1, bb = ((CID) & 1) * 4;                                 \
    unsigned p01 = __float_as_uint((C).x), p23 = __float_as_uint((C).y);       \
    short* ab = (short*)Abuf;                                                  \
    ab[(bb+0)*AST + 64 + uu] = (short)(p01 & 0xffff);                          \
    ab[(bb+1)*AST + 64 + uu] = (short)(p01 >> 16);                             \
    ab[(bb+2)*AST + 64 + uu] = (short)(p23 & 0xffff);                          \
    ab[(bb+3)*AST + 64 + uu] = (short)(p23 >> 16);                             \
    if (uu / UPG == wg) {  /* distributed hid1 by unit-slice */                \
      float* op = out + (size_t)(b0+bb)*(TT*HH) + (size_t)s*HH + uu;           \
      __builtin_nontemporal_store(__uint_as_float(p01 << 16), op);             \
      __builtin_nontemporal_store(__uint_as_float(p01 & 0xffff0000u), op + (size_t)TT*HH); \
      __builtin_nontemporal_store(__uint_as_float(p23 << 16), op + 2*(size_t)TT*HH);       \
      __builtin_nontemporal_store(__uint_as_float(p23 & 0xffff0000u), op + 3*(size_t)TT*HH); \
    }                                                                          \
  } while (0)
      UNPACK(c0v, tid);
      if (tid < CPG-512) UNPACK(c1v, tid+512);
#undef UNPACK
    }
    float xr = 0.f;                      // x_{s+1} -> reg (latency hides here)
    if (s+1 < TT && tid < MB*3)
      xr = strks[(size_t)(b0 + tid/3)*(TT*3) + (size_t)(s+1)*3 + (tid%3)];
    __syncthreads();   // S4: Abuf h-region complete

    // ---- wave 7: p_s = Wp·h_s  ||  waves 0-6: h-part of gates_{s+1}
    if (wid == 7) {
      const __hip_bfloat16* prow = Abuf + nn*AST + 64 + bq*8;
      f32x4 pa0 = {pbias0,pbias0,pbias0,pbias0};
      f32x4 pa1 = {pbias1,pbias1,pbias1,pbias1};
      #pragma unroll
      for (int kt = 0; kt < 13; ++kt) {
        bf16x8 af = *(const bf16x8*)(prow + kt*32);
        pa0 = __builtin_amdgcn_mfma_f32_16x16x32_bf16(af, wreg[kt],    pa0, 0, 0, 0);
        pa1 = __builtin_amdgcn_mfma_f32_16x16x32_bf16(af, wreg[13+kt], pa1, 0, 0, 0);
      }
      #pragma unroll
      for (int r = 0; r < 4; ++r) {
        int row = 4*bq + r;
        if (row < MB) {
          pbuf[nn*MB + row] = pa0[r];
          if (nn < 14) pbuf[(16+nn)*MB + row] = pa1[r];
        }
      }
    } else if (s+1 < TT) {
      const __hip_bfloat16* arow = Abuf + nn*AST + bq*8;
      gacc0 = (f32x4){bias0,bias0,bias0,bias0};
      gacc1 = (f32x4){bias1,bias1,bias1,bias1};
      #pragma unroll
      for (int kt = 2; kt < NKT; ++kt) {
        bf16x8 af = *(const bf16x8*)(arow + kt*32);
        gacc0 = __builtin_amdgcn_mfma_f32_16x16x32_bf16(af, wreg[kt], gacc0, 0, 0, 0);
        if (has1)
          gacc1 = __builtin_amdgcn_mfma_f32_16x16x32_bf16(af, wreg[NKT+kt], gacc1, 0, 0, 0);
      }
    }
    __syncthreads();   // S5: pbuf ready

    // ---- window (wave w owns batch w)
    if (s+1 < TT && tid < MB*3)
      Abuf[(tid/3)*AST + (tid%3)] = __float2bfloat16(xr);   // stage x_{s+1}
    {
      const int bw = wid;
      if (lane < 30) {
        float e = __expf(pbuf[lane*MB + bw]);
        if (lane < 10)      avb[lane*MB + bw] = e;
        else if (lane < 20) bvb[(lane-10)*MB + bw] = e;
        else                kvb[(lane-20)*MB + bw] += e;
      }
      { // phi: single iteration, uu = lane in [0,64)
        float sv = 0.f;
        #pragma unroll
        for (int j = 0; j < KK; ++j) {
          float d = kvb[j*MB+bw] - (float)lane;
          sv += avb[j*MB+bw] * __expf(-bvb[j*MB+bw]*d*d);
        }
        sv *= scaleb[bw];
        phib[bw*66 + lane] = sv;
        if (s == TT-1 && bw == wg) {
          out[O_PHI + (size_t)(b0+bw)*(SL+1) + lane] = sv;
          if (lane == 0) {   // phi[64] only needed for the final O_PHI row
            float s64 = 0.f;
            #pragma unroll
            for (int j = 0; j < KK; ++j) {
              float d = kvb[j*MB+bw] - 64.f;
              s64 += avb[j*MB+bw] * __expf(-bvb[j*MB+bw]*d*d);
            }
            out[O_PHI + (size_t)(b0+bw)*(SL+1) + SL] = s64 * scaleb[bw];
          }
        }
      }
      if (lane < AA) {
        const int a = lane;
        const int rot = a & 7;             // rotate chunk order: decorrelate banks
        const u32x4* orow = (const u32x4*)(ohb + (bw*AA + a)*OHST);
        const float* ph = phib + bw*66;
        float sv0 = 0.f, sv1 = 0.f;
        #pragma unroll
        for (int ci = 0; ci < 8; ++ci) {
          int c = (ci + rot) & 7;
          u32x4 v = orow[c];
          #pragma unroll
          for (int q = 0; q < 4; ++q) {
            unsigned p = v[q];
            sv0 = fmaf(__uint_as_float(p << 16),         ph[c*8 + 2*q],     sv0);
            sv1 = fmaf(__uint_as_float(p & 0xffff0000u), ph[c*8 + 2*q + 1], sv1);
          }
        }
        float sv = sv0 + sv1;
        Abuf[bw*AST + 3 + a] = __float2bfloat16(sv);
        if (bw == wg) {   // distributed win_vec: WG w writes batch w
          __builtin_nontemporal_store(sv,
              out + O_WIN + (size_t)(b0+bw)*(TT*AA) + (size_t)s*AA + a);
          if (s == TT-1) out[O_WF + (size_t)(b0+bw)*AA + a] = sv;
        }
      }
    }
    __syncthreads();   // S6: w_s (+x_{s+1}) staged in Abuf

    // ---- xw-part of gates_{s+1} + activations + publish h_{s+1}
    if (s+1 < TT && wid < TPW) {
      const __hip_bfloat16* arow = Abuf + nn*AST + bq*8;
      #pragma unroll
      for (int kt = 0; kt < 2; ++kt) {
        bf16x8 af = *(const bf16x8*)(arow + kt*32);
        gacc0 = __builtin_amdgcn_mfma_f32_16x16x32_bf16(af, wreg[kt], gacc0, 0, 0, 0);
        if (has1)
          gacc1 = __builtin_amdgcn_mfma_f32_16x16x32_bf16(af, wreg[NKT+kt], gacc1, 0, 0, 0);
      }
      ACT_PUBLISH(gacc0, u0, cst0, chn, s+2, (s+1 == TT-1));
      if (has1) ACT_PUBLISH(gacc1, u1, cst1, chn, s+2, (s+1 == TT-1));
    }
    // no barrier: next collect writes h-region [64,464); xw reads k<64 only
  }
#undef ACT_PUBLISH

  __syncthreads();
  if (tid < KK)   // WG wg writes k_f for batch wg
    out[O_KF + (size_t)(b0+wg)*KK + tid] = kvb[tid*MB + wg];
}

extern "C" void kernel_launch(void* const* d_in, const int* in_sizes, int n_in,
                              void* d_out, int out_size, void* d_ws, size_t ws_size,
                              hipStream_t stream) {
  const float* strks   = (const float*)d_in[0];
  const float* onehots = (const float*)d_in[1];
  const float* sents_m = (const float*)d_in[2];
  const float* w_prev  = (const float*)d_in[3];
  const float* k_prev  = (const float*)d_in[4];
  const float* h0      = (const float*)d_in[5];
  const float* c0      = (const float*)d_in[6];
  const float* W_ih    = (const float*)d_in[7];
  const float* b_ih    = (const float*)d_in[8];
  const float* W_hh    = (const float*)d_in[9];
  const float* b_hh    = (const float*)d_in[10];
  const float* Wp      = (const float*)d_in[11];
  const float* bp      = (const float*)d_in[12];

  hipFuncSetAttribute((const void*)lstm_split,
                      hipFuncAttributeMaxDynamicSharedMemorySize, SMEM_BYTES);
  hipMemsetAsync(d_ws, 0, HCH_N*4, stream);   // stale-seq guard across replays
  int prep_threads = GATE_FRAGS*64 + NPF*64;
  hipLaunchKernelGGL(prep_pack, dim3((prep_threads+255)/256), dim3(256), 0, stream,
                     W_ih, W_hh, Wp, (short*)d_ws);
  hipLaunchKernelGGL(lstm_split, dim3(NG*GWG), dim3(NTHR), SMEM_BYTES, stream,
                     strks, onehots, sents_m, w_prev, k_prev, h0, c0,
                     b_ih, b_hh, bp, (float*)d_out, (float*)d_ws);
}

// Round 14
// 4506.747 us; speedup vs baseline: 141.5703x; 141.5703x over previous
//
#include <hip/hip_runtime.h>
#include <hip/hip_bf16.h>
#include <math.h>

#define BATCH 128
#define TT 800
#define SL 64
#define AA 60
#define HH 400
#define KK 10
#define MB 8            // batches per group
#define NG 16           // groups
#define GWG 8           // WGs per group (NG*GWG = 128 blocks)
#define NTHR 512
#define TPW 7           // gate waves (each owns up to 2 tiles); wave 7 = p-dot
#define NTILE 104       // 100 real + 4 dummy unit-gate tiles (13 per WG)
#define NKT 15          // K tiles: K=480 = [x:3|w:60|0:1|h:400|0:16]
#define AST 488         // Abuf row stride (shorts)
#define NPF 26          // Wp fragments
#define OHST 72         // transposed onehots l-stride (shorts)
#define UPG 50          // hid1 unit-slice per WG (HH/GWG)
#define CPG 800         // h-chunks per group (400 units x 2 batch-quads)

#define O_HF   (BATCH*TT*HH)
#define O_CF   (O_HF + BATCH*HH)
#define O_WIN  (O_CF + BATCH*HH)
#define O_WF   (O_WIN + BATCH*TT*AA)
#define O_KF   (O_WF + BATCH*AA)
#define O_PHI  (O_KF + BATCH*KK)

// ws: tagged h-chunks [2][NG][CPG][4 floats] | gate pack | Wp pack
#define HCH_N (2*NG*CPG*4)              // 102400 floats (zeroed each launch)
#define PK_S  (HCH_N*2)
#define GATE_FRAGS (NTILE*NKT)
#define PPK_S (PK_S + GATE_FRAGS*512)

// dynamic LDS partition (bytes)
#define SM_ABUF  0                            // 16 rows (8 real) x AST shorts
#define SM_OHB   (SM_ABUF + 16*AST*2)         // 15616
#define SM_PHIB  (SM_OHB + MB*AA*OHST*2)      // 84736
#define SM_PBUF  (SM_PHIB + MB*66*4)          // 86848
#define SM_AVB   (SM_PBUF + 30*MB*4)          // 87808
#define SM_BVB   (SM_AVB + KK*MB*4)           // 88128
#define SM_KVB   (SM_BVB + KK*MB*4)           // 88448
#define SM_SCALE (SM_KVB + KK*MB*4)           // 88768
#define SMEM_BYTES (SM_SCALE + 64)            // 88832

typedef __attribute__((ext_vector_type(8))) short bf16x8;
typedef __attribute__((ext_vector_type(4))) float f32x4;
typedef __attribute__((ext_vector_type(4))) unsigned u32x4;

__device__ __forceinline__ void llc_ld4(f32x4& r, const float* p) {
  asm volatile("global_load_dwordx4 %0, %1, off sc1" : "=&v"(r) : "v"(p) : "memory");
}
__device__ __forceinline__ void llc_st4(float* p, f32x4 v) {
  asm volatile("global_store_dwordx4 %0, %1, off sc1" :: "v"(p), "v"(v) : "memory");
}
__device__ __forceinline__ void vm_drain() {
  asm volatile("s_waitcnt vmcnt(0)" ::: "memory");
  __builtin_amdgcn_sched_barrier(0);
}
__device__ __forceinline__ unsigned bf16bits(float x) {
  __hip_bfloat16 hb = __float2bfloat16(x);
  return (unsigned)*reinterpret_cast<unsigned short*>(&hb);
}

__global__ void prep_pack(const float* __restrict__ W_ih, const float* __restrict__ W_hh,
                          const float* __restrict__ Wp, short* __restrict__ dst) {
  int tid = blockIdx.x*256 + threadIdx.x;
  const int NWT = GATE_FRAGS*64;
  if (tid < NWT) {
    int l = tid & 63;
    int kt = (tid >> 6) % NKT;
    int tt = (tid >> 6) / NKT;
    int nn = l & 15;
    int gt = nn >> 2, du = nn & 3;
    int u = tt*4 + du;
    int kb = kt*32 + (l>>4)*8;
    __align__(16) short v[8];
    #pragma unroll
    for (int j = 0; j < 8; ++j) {
      int k = kb + j;
      float x = 0.f;
      if (u < HH) {
        if (k < 63) x = W_ih[(size_t)(gt*HH+u)*63 + k];
        else if (k >= 64 && k < 464) x = W_hh[(size_t)(gt*HH+u)*HH + (k-64)];
      }
      __hip_bfloat16 hb = __float2bfloat16(x);
      v[j] = *reinterpret_cast<short*>(&hb);
    }
    *(bf16x8*)(dst + (size_t)PK_S + (size_t)tid*8) = *(const bf16x8*)v;
  } else if (tid < NWT + NPF*64) {
    int r = tid - NWT;
    int l = r & 63;
    int idx = r >> 6;
    int kt = idx % 13;
    int tp = idx / 13;
    int jj = tp*16 + (l&15);
    int kb = (kt+2)*32 + (l>>4)*8;
    __align__(16) short v[8];
    #pragma unroll
    for (int j = 0; j < 8; ++j) {
      int k = kb + j;
      float x = (jj < 3*KK && k >= 64 && k < 464) ? Wp[(size_t)jj*HH + (k-64)] : 0.f;
      __hip_bfloat16 hb = __float2bfloat16(x);
      v[j] = *reinterpret_cast<short*>(&hb);
    }
    *(bf16x8*)(dst + (size_t)PPK_S + (size_t)r*8) = *(const bf16x8*)v;
  }
}

__global__ __launch_bounds__(NTHR, 1) void lstm_split(
    const float* __restrict__ strks, const float* __restrict__ onehots,
    const float* __restrict__ sents_m, const float* __restrict__ w_prev,
    const float* __restrict__ k_prev, const float* __restrict__ h0,
    const float* __restrict__ c0, const float* __restrict__ b_ih,
    const float* __restrict__ b_hh, const float* __restrict__ bp,
    float* __restrict__ out, float* __restrict__ ws)
{
  const int g  = blockIdx.x & 15;       // 16 groups (co-XCD-ish under round-robin)
  const int wg = blockIdx.x >> 4;       // 8 WGs per group
  const int b0 = g*MB;
  const int tid = threadIdx.x;
  const int lane = tid & 63;
  const int wid = tid >> 6;
  const int nn = lane & 15, gt = nn >> 2, du = nn & 3, bq = lane >> 4;

  float* hch = ws;
  const __hip_bfloat16* gpk  = (const __hip_bfloat16*)((const short*)ws + PK_S);
  const __hip_bfloat16* gppk = (const __hip_bfloat16*)((const short*)ws + PPK_S);

  extern __shared__ __align__(16) char smem[];
  __hip_bfloat16* Abuf = (__hip_bfloat16*)(smem + SM_ABUF);   // [16 rows][k]
  __hip_bfloat16* ohb  = (__hip_bfloat16*)(smem + SM_OHB);    // [b][a][OHST]
  float* phib   = (float*)(smem + SM_PHIB);                   // [b][66]
  float* pbuf   = (float*)(smem + SM_PBUF);                   // [j][b]
  float* avb    = (float*)(smem + SM_AVB);
  float* bvb    = (float*)(smem + SM_BVB);
  float* kvb    = (float*)(smem + SM_KVB);
  float* scaleb = (float*)(smem + SM_SCALE);

  // gate tiles: 13 per WG, 2 per wave (wave 6 gets 1)
  const int tbase = wg*13 + wid*2;
  const bool has1 = (wid < 6);
  const int u0 = (wid < TPW) ? (tbase*4 + du) : HH;
  const int u1 = (wid < TPW && has1) ? ((tbase+1)*4 + du) : HH;

  float bias0 = 0.f, bias1 = 0.f, cst0[4] = {0,0,0,0}, cst1[4] = {0,0,0,0};
  if (wid < TPW) {
    if (u0 < HH) bias0 = b_ih[gt*HH+u0] + b_hh[gt*HH+u0];
    if (u1 < HH) bias1 = b_ih[gt*HH+u1] + b_hh[gt*HH+u1];
    if (bq < 2) {
      #pragma unroll
      for (int r = 0; r < 4; ++r) {
        if (u0 < HH) cst0[r] = c0[(size_t)(b0+4*bq+r)*HH + u0];
        if (u1 < HH) cst1[r] = c0[(size_t)(b0+4*bq+r)*HH + u1];
      }
    }
  }
  float pbias0 = 0.f, pbias1 = 0.f;
  if (wid == 7) {
    if (nn < 3*KK - 16) pbias1 = bp[16 + nn];
    pbias0 = bp[nn];
  }

  // weights -> registers once; wreg unioned: gates use [0..29], wave7 uses [0..25]
  bf16x8 wreg[30];
  if (wid < TPW) {
    const __hip_bfloat16* base0 = gpk + ((size_t)tbase*NKT*64 + lane)*8;
    #pragma unroll
    for (int kt = 0; kt < NKT; ++kt) wreg[kt] = *(const bf16x8*)(base0 + (size_t)kt*512);
    if (has1) {
      const __hip_bfloat16* base1 = gpk + ((size_t)(tbase+1)*NKT*64 + lane)*8;
      #pragma unroll
      for (int kt = 0; kt < NKT; ++kt) wreg[NKT+kt] = *(const bf16x8*)(base1 + (size_t)kt*512);
    }
  } else {
    const __hip_bfloat16* base = gppk + (size_t)lane*8;
    #pragma unroll
    for (int i = 0; i < NPF; ++i) wreg[i] = *(const bf16x8*)(base + (size_t)i*512);
  }

  // prologue: Abuf rows 0..7 = [x_0 | w_prev | 0 | h0 | 0], rows 8..15 zero
  for (int i = tid; i < 16*AST; i += NTHR) {
    int b = i / AST, k = i % AST;
    float v = 0.f;
    if (b < MB) {
      if (k < 3) v = strks[(size_t)(b0+b)*(TT*3) + k];
      else if (k < 63) v = w_prev[(size_t)(b0+b)*AA + (k-3)];
      else if (k >= 64 && k < 464) v = h0[(size_t)(b0+b)*HH + (k-64)];
    }
    Abuf[i] = __float2bfloat16(v);
  }
  for (int i = tid; i < MB*SL*AA; i += NTHR) {
    int b = i / (SL*AA), r = i % (SL*AA);
    int l = r / AA, a = r % AA;
    ohb[(b*AA + a)*OHST + l] = __float2bfloat16(onehots[(size_t)b0*SL*AA + i]);
  }
  for (int i = tid; i < KK*MB; i += NTHR)
    kvb[(i>>3)*MB + (i&7)] = k_prev[(size_t)(b0+(i&7))*KK + (i>>3)];
  if (tid < MB) {
    float s = 0.f;
    for (int l = 0; l < SL; ++l) s += sents_m[(size_t)(b0+tid)*SL + l];
    scaleb[tid] = (float)SL / s;
  }
  __syncthreads();

#define ACT_PUBLISH(ACC, UU, CST, CHB, SEQTAG, WRITE_FINAL) do {               \
    float vv[4], hq[4];                                                        \
    _Pragma("unroll") for (int r = 0; r < 4; ++r) {                            \
      float v = (ACC)[r];                                                      \
      float sg = 1.f/(1.f + __expf(gt==2 ? -2.f*v : -v));                      \
      vv[r] = (gt==2) ? 2.f*sg - 1.f : sg;                                     \
    }                                                                          \
    _Pragma("unroll") for (int r = 0; r < 4; ++r) {                            \
      float v = vv[r];                                                         \
      float x4 = __shfl_xor(v,4), x8 = __shfl_xor(v,8), x12 = __shfl_xor(v,12);\
      float iv = (gt==0)?v  :(gt==1)?x4 :(gt==2)?x8 :x12;                      \
      float fv = (gt==0)?x4 :(gt==1)?v  :(gt==2)?x12:x8;                       \
      float gv = (gt==0)?x8 :(gt==1)?x12:(gt==2)?v  :x4;                       \
      float ov = (gt==0)?x12:(gt==1)?x8 :(gt==2)?x4 :v;                        \
      float c = fv*(CST)[r] + iv*gv;                                           \
      (CST)[r] = c;                                                            \
      hq[r] = ov * (2.f/(1.f + __expf(-2.f*c)) - 1.f);                         \
    }                                                                          \
    if (gt == 0 && bq < 2 && (UU) < HH) {                                      \
      unsigned q01 = bf16bits(hq[0]) | (bf16bits(hq[1]) << 16);                \
      unsigned q23 = bf16bits(hq[2]) | (bf16bits(hq[3]) << 16);                \
      f32x4 ch = { __uint_as_float(q01), __uint_as_float(q23),                 \
                   __int_as_float(SEQTAG), 0.f };                              \
      llc_st4((CHB) + (size_t)4*((UU)*2 + bq), ch);                            \
      if (WRITE_FINAL) {                                                       \
        _Pragma("unroll") for (int r = 0; r < 4; ++r) {                        \
          out[O_HF + (size_t)(b0+4*bq+r)*HH + (UU)] = hq[r];                   \
          out[O_CF + (size_t)(b0+4*bq+r)*HH + (UU)] = (CST)[r];                \
        }                                                                      \
      }                                                                        \
    }                                                                          \
  } while (0)

  // prologue gates: full K -> publish h_0 (tag 1, parity 0)
  f32x4 gacc0, gacc1;
  if (wid < TPW) {
    const __hip_bfloat16* arow = Abuf + nn*AST + bq*8;
    gacc0 = (f32x4){bias0,bias0,bias0,bias0};
    gacc1 = (f32x4){bias1,bias1,bias1,bias1};
    #pragma unroll
    for (int kt = 0; kt < NKT; ++kt) {
      bf16x8 af = *(const bf16x8*)(arow + kt*32);
      gacc0 = __builtin_amdgcn_mfma_f32_16x16x32_bf16(af, wreg[kt], gacc0, 0, 0, 0);
      if (has1)
        gacc1 = __builtin_amdgcn_mfma_f32_16x16x32_bf16(af, wreg[NKT+kt], gacc1, 0, 0, 0);
    }
    float* chb0 = hch + (size_t)g*(CPG*4);
    ACT_PUBLISH(gacc0, u0, cst0, chb0, 1, false);
    if (has1) ACT_PUBLISH(gacc1, u1, cst1, chb0, 1, false);
  }
  __syncthreads();   // prologue h-region reads done before collect overwrites

  for (int s = 0; s < TT; ++s) {
    float* chb = hch + (size_t)(((s  )&1)*NG + g)*(CPG*4);  // h_s
    float* chn = hch + (size_t)(((s+1)&1)*NG + g)*(CPG*4);  // h_{s+1}

    // ---- collect h_s: speculative tagged reads (800 chunks, 2 slots/thread)
    {
      const int want = s+1;
      f32x4 c0v, c1v;
      int d0 = 0, d1 = (tid < CPG-512) ? 0 : 1;
      for (int it = 0; it < (1<<12); ++it) {
        if (!d0) llc_ld4(c0v, chb + 4*(size_t)tid);
        if (!d1) llc_ld4(c1v, chb + 4*(size_t)(tid+512));
        vm_drain();
        d0 |= (__float_as_int(c0v.z) == want);
        d1 |= (__float_as_int(c1v.z) == want);
        if (d0 & d1) break;
        if (it) __builtin_amdgcn_s_sleep(1);
      }
#define UNPACK(C, CID) do {                                                    \
    int uu = (CID) >> 1, bb = ((CID) & 1) * 4;                                 \
    unsigned p01 = __float_as_uint((C).x), p23 = __float_as_uint((C).y);       \
    short* ab = (short*)Abuf;                                                  \
    ab[(bb+0)*AST + 64 + uu] = (short)(p01 & 0xffff);                          \
    ab[(bb+1)*AST + 64 + uu] = (short)(p01 >> 16);                             \
    ab[(bb+2)*AST + 64 + uu] = (short)(p23 & 0xffff);                          \
    ab[(bb+3)*AST + 64 + uu] = (short)(p23 >> 16);                             \
    if (uu / UPG == wg) {  /* distributed hid1 by unit-slice */                \
      float* op = out + (size_t)(b0+bb)*(TT*HH) + (size_t)s*HH + uu;           \
      __builtin_nontemporal_store(__uint_as_float(p01 << 16), op);             \
      __builtin_nontemporal_store(__uint_as_float(p01 & 0xffff0000u), op + (size_t)TT*HH); \
      __builtin_nontemporal_store(__uint_as_float(p23 << 16), op + 2*(size_t)TT*HH);       \
      __builtin_nontemporal_store(__uint_as_float(p23 & 0xffff0000u), op + 3*(size_t)TT*HH); \
    }                                                                          \
  } while (0)
      UNPACK(c0v, tid);
      if (tid < CPG-512) UNPACK(c1v, tid+512);
#undef UNPACK
    }
    float xr = 0.f;                      // x_{s+1} -> reg (latency hides here)
    if (s+1 < TT && tid < MB*3)
      xr = strks[(size_t)(b0 + tid/3)*(TT*3) + (size_t)(s+1)*3 + (tid%3)];
    __syncthreads();   // S4: Abuf h-region complete

    // ---- wave 7: p_s = Wp·h_s  ||  waves 0-6: h-part of gates_{s+1}
    if (wid == 7) {
      const __hip_bfloat16* prow = Abuf + nn*AST + 64 + bq*8;
      f32x4 pa0 = {pbias0,pbias0,pbias0,pbias0};
      f32x4 pa1 = {pbias1,pbias1,pbias1,pbias1};
      #pragma unroll
      for (int kt = 0; kt < 13; ++kt) {
        bf16x8 af = *(const bf16x8*)(prow + kt*32);
        pa0 = __builtin_amdgcn_mfma_f32_16x16x32_bf16(af, wreg[kt],    pa0, 0, 0, 0);
        pa1 = __builtin_amdgcn_mfma_f32_16x16x32_bf16(af, wreg[13+kt], pa1, 0, 0, 0);
      }
      #pragma unroll
      for (int r = 0; r < 4; ++r) {
        int row = 4*bq + r;
        if (row < MB) {
          pbuf[nn*MB + row] = pa0[r];
          if (nn < 14) pbuf[(16+nn)*MB + row] = pa1[r];
        }
      }
    } else if (s+1 < TT) {
      const __hip_bfloat16* arow = Abuf + nn*AST + bq*8;
      gacc0 = (f32x4){bias0,bias0,bias0,bias0};
      gacc1 = (f32x4){bias1,bias1,bias1,bias1};
      #pragma unroll
      for (int kt = 2; kt < NKT; ++kt) {
        bf16x8 af = *(const bf16x8*)(arow + kt*32);
        gacc0 = __builtin_amdgcn_mfma_f32_16x16x32_bf16(af, wreg[kt], gacc0, 0, 0, 0);
        if (has1)
          gacc1 = __builtin_amdgcn_mfma_f32_16x16x32_bf16(af, wreg[NKT+kt], gacc1, 0, 0, 0);
      }
    }
    __syncthreads();   // S5: pbuf ready

    // ---- window (wave w owns batch w)
    if (s+1 < TT && tid < MB*3)
      Abuf[(tid/3)*AST + (tid%3)] = __float2bfloat16(xr);   // stage x_{s+1}
    {
      const int bw = wid;
      if (lane < 30) {
        float e = __expf(pbuf[lane*MB + bw]);
        if (lane < 10)      avb[lane*MB + bw] = e;
        else if (lane < 20) bvb[(lane-10)*MB + bw] = e;
        else                kvb[(lane-20)*MB + bw] += e;
      }
      for (int uu = lane; uu <= SL; uu += 64) {
        float sv = 0.f;
        #pragma unroll
        for (int j = 0; j < KK; ++j) {
          float d = kvb[j*MB+bw] - (float)uu;
          sv += avb[j*MB+bw] * __expf(-bvb[j*MB+bw]*d*d);
        }
        sv *= scaleb[bw];
        phib[bw*66 + uu] = sv;
        if (s == TT-1 && bw == wg) out[O_PHI + (size_t)(b0+bw)*(SL+1) + uu] = sv;
      }
      if (lane < AA) {
        const int a = lane;
        const u32x4* orow = (const u32x4*)(ohb + (bw*AA + a)*OHST);
        const float* ph = phib + bw*66;
        float sv0 = 0.f, sv1 = 0.f;   // split serial fma chain
        #pragma unroll
        for (int c = 0; c < 4; ++c) {
          u32x4 v = orow[c];
          #pragma unroll
          for (int q = 0; q < 4; ++q) {
            unsigned p = v[q];
            sv0 = fmaf(__uint_as_float(p << 16),         ph[c*8 + 2*q],     sv0);
            sv1 = fmaf(__uint_as_float(p & 0xffff0000u), ph[c*8 + 2*q + 1], sv1);
          }
        }
        #pragma unroll
        for (int c = 4; c < 8; ++c) {
          u32x4 v = orow[c];
          #pragma unroll
          for (int q = 0; q < 4; ++q) {
            unsigned p = v[q];
            sv0 = fmaf(__uint_as_float(p << 16),         ph[c*8 + 2*q],     sv0);
            sv1 = fmaf(__uint_as_float(p & 0xffff0000u), ph[c*8 + 2*q + 1], sv1);
          }
        }
        float sv = sv0 + sv1;
        Abuf[bw*AST + 3 + a] = __float2bfloat16(sv);
        if (bw == wg) {   // distributed win_vec: WG w writes batch w
          __builtin_nontemporal_store(sv,
              out + O_WIN + (size_t)(b0+bw)*(TT*AA) + (size_t)s*AA + a);
          if (s == TT-1) out[O_WF + (size_t)(b0+bw)*AA + a] = sv;
        }
      }
    }
    __syncthreads();   // S6: w_s (+x_{s+1}) staged in Abuf

    // ---- xw-part of gates_{s+1} + activations + publish h_{s+1}
    if (s+1 < TT && wid < TPW) {
      const __hip_bfloat16* arow = Abuf + nn*AST + bq*8;
      #pragma unroll
      for (int kt = 0; kt < 2; ++kt) {
        bf16x8 af = *(const bf16x8*)(arow + kt*32);
        gacc0 = __builtin_amdgcn_mfma_f32_16x16x32_bf16(af, wreg[kt], gacc0, 0, 0, 0);
        if (has1)
          gacc1 = __builtin_amdgcn_mfma_f32_16x16x32_bf16(af, wreg[NKT+kt], gacc1, 0, 0, 0);
      }
      ACT_PUBLISH(gacc0, u0, cst0, chn, s+2, (s+1 == TT-1));
      if (has1) ACT_PUBLISH(gacc1, u1, cst1, chn, s+2, (s+1 == TT-1));
    }
    // no barrier: next collect writes h-region [64,464); xw reads k<64 only
  }
#undef ACT_PUBLISH

  __syncthreads();
  if (tid < KK)   // WG wg writes k_f for batch wg
    out[O_KF + (size_t)(b0+wg)*KK + tid] = kvb[tid*MB + wg];
}

extern "C" void kernel_launch(void* const* d_in, const int* in_sizes, int n_in,
                              void* d_out, int out_size, void* d_ws, size_t ws_size,
                              hipStream_t stream) {
  const float* strks   = (const float*)d_in[0];
  const float* onehots = (const float*)d_in[1];
  const float* sents_m = (const float*)d_in[2];
  const float* w_prev  = (const float*)d_in[3];
  const float* k_prev  = (const float*)d_in[4];
  const float* h0      = (const float*)d_in[5];
  const float* c0      = (const float*)d_in[6];
  const float* W_ih    = (const float*)d_in[7];
  const float* b_ih    = (const float*)d_in[8];
  const float* W_hh    = (const float*)d_in[9];
  const float* b_hh    = (const float*)d_in[10];
  const float* Wp      = (const float*)d_in[11];
  const float* bp      = (const float*)d_in[12];

  hipFuncSetAttribute((const void*)lstm_split,
                      hipFuncAttributeMaxDynamicSharedMemorySize, SMEM_BYTES);
  hipMemsetAsync(d_ws, 0, HCH_N*4, stream);   // stale-seq guard across replays
  int prep_threads = GATE_FRAGS*64 + NPF*64;
  hipLaunchKernelGGL(prep_pack, dim3((prep_threads+255)/256), dim3(256), 0, stream,
                     W_ih, W_hh, Wp, (short*)d_ws);
  hipLaunchKernelGGL(lstm_split, dim3(NG*GWG), dim3(NTHR), SMEM_BYTES, stream,
                     strks, onehots, sents_m, w_prev, k_prev, h0, c0,
                     b_ih, b_hh, bp, (float*)d_out, (float*)d_ws);
}